// Round 2
// baseline (1715.162 us; speedup 1.0000x reference)
//
#include <hip/hip_runtime.h>
#include <cmath>

#define D_    1024
#define B_    128
#define N_    576
#define ROWS_ (B_*N_)
#define TWOD_ 2048
#define TAU_  1e-5f
#define NB_   512
#define NT_   256

__device__ __forceinline__ float wrsum(float v){
  #pragma unroll
  for (int m=32;m;m>>=1) v += __shfl_xor(v,m,64);
  return v;
}
__device__ __forceinline__ float wrmax(float v){
  #pragma unroll
  for (int m=32;m;m>>=1) v = fmaxf(v,__shfl_xor(v,m,64));
  return v;
}

// device-scope grid barrier: monotonic counter, all NB_ blocks co-resident
// (guaranteed by __launch_bounds__(256,2): 2 blocks/CU x 256 CU = 512).
__device__ __forceinline__ void gsync(int* bar, int phase){
  __syncthreads();
  if (threadIdx.x==0){
    __threadfence();  // make this block's prior stores visible device-wide
    __hip_atomic_fetch_add(bar, 1, __ATOMIC_ACQ_REL, __HIP_MEMORY_SCOPE_AGENT);
    while (__hip_atomic_load(bar, __ATOMIC_ACQUIRE, __HIP_MEMORY_SCOPE_AGENT) < NB_*phase)
      __builtin_amdgcn_s_sleep(2);
  }
  __syncthreads();
}

// one 2-row x 128-col GEMM tile: C[2,NOUT tile] = act((A(+A2))@W + bias)
// TMODE 0: W[k*NOUT+col]; TMODE 1: W[col*D_+k] (A@W^T). DOP0: fuse p0 += relu(o)*wd2.
template<int NOUT,int ACT,int TMODE,int FUSEADD,int DOP0>
__device__ void gemm_unit(const float* A, const float* A2, const float* W,
    const float* bias, float* C, int bx, int by, float* a_s,
    const float* wd2, float* p0){
  int tid = threadIdx.x;
  int r0 = by*2;
  const float4* A4 = (const float4*)(A + (size_t)r0*D_);
  float4* s4 = (float4*)a_s;
  if (FUSEADD){
    const float4* B4 = (const float4*)(A2 + (size_t)r0*D_);
    for (int i=tid;i<512;i+=NT_){ float4 a=A4[i], b=B4[i];
      s4[i] = make_float4(a.x+b.x,a.y+b.y,a.z+b.z,a.w+b.w); }
  } else {
    for (int i=tid;i<512;i+=NT_) s4[i]=A4[i];
  }
  __syncthreads();
  int rsel = tid>>7;
  int row = r0 + rsel;
  int col = bx*128 + (tid&127);
  const float* arow = a_s + rsel*D_;
  float acc0=0.f, acc1=0.f;
  if (TMODE==0){
    const float* wp = W + col;
    #pragma unroll 8
    for (int k=0;k<D_;k+=2){
      acc0 = fmaf(arow[k],   wp[(size_t)k*NOUT],     acc0);
      acc1 = fmaf(arow[k+1], wp[(size_t)(k+1)*NOUT], acc1);
    }
  } else {
    const float* wp = W + (size_t)col*D_;
    #pragma unroll 4
    for (int k=0;k<D_;k+=4){
      float4 wv = *(const float4*)(wp+k);
      acc0=fmaf(arow[k],  wv.x,acc0); acc1=fmaf(arow[k+1],wv.y,acc1);
      acc0=fmaf(arow[k+2],wv.z,acc0); acc1=fmaf(arow[k+3],wv.w,acc1);
    }
  }
  float o = acc0+acc1 + (bias ? bias[col] : 0.f);
  if (ACT==1) o = o/(1.f+expf(-o));
  C[(size_t)row*NOUT + col] = o;
  if (DOP0){
    float c = fmaxf(o,0.f)*wd2[col];
    c = wrsum(c);
    if ((tid&63)==0) atomicAdd(&p0[row], c);
  }
  __syncthreads();  // protect smem before reuse
}

__global__ __launch_bounds__(NT_,2) void k_mega(
  const float* __restrict__ x, const int* __restrict__ ts,
  const float* __restrict__ text, const float* __restrict__ imgf,
  const float* __restrict__ Wq, const float* __restrict__ Wk,
  const float* __restrict__ Wv, const float* __restrict__ Wp, const float* __restrict__ bp,
  const float* __restrict__ Wt1, const float* __restrict__ bt1,
  const float* __restrict__ Wt2, const float* __restrict__ bt2,
  const float* __restrict__ Wd1, const float* __restrict__ bd1,
  const float* __restrict__ Wd2, const float* __restrict__ bd2,
  float* __restrict__ out, float* __restrict__ ws)
{
  __shared__ __align__(16) float smem[8256];   // 33 KB: corr img[1024][8] is the max user
  float* temb  = ws;
  float* h1    = ws + 131072;
  float* cond  = ws + 262144;
  float* q     = ws + 393216;
  float* kq    = ws + 524288;
  float* wimg  = ws + 655360;
  float* v     = ws + 786432;
  float* nemb  = ws + 917504;
  float* rb    = ws + 1048576;   // [B][2048]
  float* sbuf  = ws + 1310720;
  float* wgt   = ws + 1384448;
  float* pcorr = ws + 1458176;
  float* liw   = ws + 1531904;
  int*   lrow  = (int*)(ws + 1605632);
  float* p0    = ws + 1679360;
  int*   cnt   = (int*)(ws + 1679488);
  int*   bar   = (int*)(ws + 1679552);

  const int bid = blockIdx.x, tid = threadIdx.x;
  const int lane = tid&63, wid = tid>>6;

  // ---- S0: prep (temb, zero pcorr/p0/cnt)
  {
    int t = bid*NT_ + tid;
    if (t >= 65536){
      int p = t - 65536, b = p>>9, i = p&511;
      float tt = (float)ts[b];
      float dv = expf((float)(2*i) * (-9.210340371976184f/1024.f));
      float a = tt*dv;
      temb[b*D_+2*i]   = sinf(a);
      temb[b*D_+2*i+1] = cosf(a);
    }
    if (t < ROWS_) pcorr[t]=0.f;
    if (t < B_)    p0[t]=0.f;
    if (t==0)      *cnt = 0;
  }
  gsync(bar,1);

  // ---- S1: gemm Wt1 (1 unit/block) + i_w logits dots (grid-stride by wave)
  gemm_unit<D_,1,0,0,0>(temb,nullptr,Wt1,bt1,h1, bid&7, bid>>3, smem, nullptr,nullptr);
  {
    int wg = bid*4 + wid;
    for (int row = wg; row < ROWS_; row += NB_*4){
      const float4* ip = (const float4*)(imgf + (size_t)row*D_);
      const float4* tp = (const float4*)(text + (size_t)(row/N_)*D_);
      float acc=0.f;
      #pragma unroll
      for (int p=0;p<4;p++){
        float4 a=ip[p*64+lane], t=tp[p*64+lane];
        acc=fmaf(a.x,t.x,acc); acc=fmaf(a.y,t.y,acc);
        acc=fmaf(a.z,t.z,acc); acc=fmaf(a.w,t.w,acc);
      }
      acc = wrsum(acc);
      if (lane==0) sbuf[row]=acc;
    }
  }
  gsync(bar,2);

  // ---- S2: gemm Wt2 -> cond; blocks<128 also do i_w softmax + build sparse list
  gemm_unit<D_,0,0,0,0>(h1,nullptr,Wt2,bt2,cond, bid&7, bid>>3, smem, nullptr,nullptr);
  if (bid < B_){
    const float* sp = sbuf + bid*N_;
    float* red = smem;
    float m=-3e38f;
    for (int i=tid;i<N_;i+=NT_) m=fmaxf(m,sp[i]);
    m = wrmax(m);
    if (lane==0) red[wid]=m;
    __syncthreads();
    m = fmaxf(fmaxf(red[0],red[1]),fmaxf(red[2],red[3]));
    __syncthreads();
    float s=0.f;
    for (int i=tid;i<N_;i+=NT_) s += expf(sp[i]-m);
    s = wrsum(s);
    if (lane==0) red[wid]=s;
    __syncthreads();
    s = red[0]+red[1]+red[2]+red[3];
    float inv = 1.f/s;
    for (int i=tid;i<N_;i+=NT_){
      float wi = expf(sp[i]-m)*inv;
      if (wi > TAU_){
        int pos = atomicAdd(cnt,1);
        if (pos < ROWS_){ lrow[pos]=bid*N_+i; liw[pos]=wi; }
      }
    }
  }
  gsync(bar,3);

  // ---- S3: q = (text+cond)@Wq
  gemm_unit<D_,0,0,1,0>(text,cond,Wq,nullptr,q, bid&7, bid>>3, smem, nullptr,nullptr);
  gsync(bar,4);

  // ---- S4: kq = q@Wk^T
  gemm_unit<D_,0,1,0,0>(q,nullptr,Wk,nullptr,kq, bid&7, bid>>3, smem, nullptr,nullptr);
  gsync(bar,5);

  // ---- S5: per-b fused attention logits + softmax2 + wimg (no atomics, no zero-init)
  if (bid < B_){
    int b = bid;
    float* kqs  = smem;                 // 1024
    float* srow = smem+1024;            // 576
    float* red  = smem+1600;            // 8
    int*   mcv  = (int*)(smem+1608);
    int*   mrow = (int*)(smem+1664);    // up to 576
    float* miw  = smem+2240;            // up to 576
    for (int i=tid;i<D_;i+=NT_) kqs[i]=kq[b*D_+i];
    for (int j=tid;j<N_;j+=NT_) srow[j]=x[b*N_+j];
    if (tid==0) *mcv=0;
    __syncthreads();
    int c = min(__hip_atomic_load(cnt,__ATOMIC_RELAXED,__HIP_MEMORY_SCOPE_AGENT), ROWS_);
    for (int e=tid;e<c;e+=NT_){
      int row=lrow[e];
      if (row/N_ == b){
        int p = atomicAdd(mcv,1);
        mrow[p]=row; miw[p]=liw[e];
      }
    }
    __syncthreads();
    int mc = *mcv;
    for (int m=0;m<mc;m++){
      int row=mrow[m];
      const float4* ip=(const float4*)(imgf+(size_t)row*D_);
      const float4* kp=(const float4*)kqs;
      float4 a=ip[tid], k=kp[tid];
      float acc=a.x*k.x+a.y*k.y+a.z*k.z+a.w*k.w;
      acc = wrsum(acc);
      if (lane==0) red[wid]=acc;
      __syncthreads();
      if (tid==0) srow[row%N_] += miw[m]*(red[0]+red[1]+red[2]+red[3]);
      __syncthreads();
    }
    float mx=-3e38f;
    for (int j=tid;j<N_;j+=NT_) mx=fmaxf(mx,srow[j]);
    mx=wrmax(mx);
    if (lane==0) red[wid]=mx;
    __syncthreads();
    mx=fmaxf(fmaxf(red[0],red[1]),fmaxf(red[2],red[3]));
    __syncthreads();
    float sum=0.f;
    for (int j=tid;j<N_;j+=NT_) sum+=expf(srow[j]-mx);
    sum=wrsum(sum);
    if (lane==0) red[wid]=sum;
    __syncthreads();
    sum=red[0]+red[1]+red[2]+red[3];
    float inv=1.f/sum;
    __syncthreads();
    for (int j=tid;j<N_;j+=NT_){
      float wv=expf(srow[j]-mx)*inv;
      wgt[b*N_+j]=wv;
      srow[j]=wv;
    }
    __syncthreads();
    float a0=0,a1=0,a2=0,a3=0;
    for (int m=0;m<mc;m++){
      int row=mrow[m];
      float coef = miw[m]*srow[row%N_];
      const float* ip = imgf + (size_t)row*D_;
      a0=fmaf(coef,ip[tid],a0);
      a1=fmaf(coef,ip[tid+256],a1);
      a2=fmaf(coef,ip[tid+512],a2);
      a3=fmaf(coef,ip[tid+768],a3);
    }
    wimg[b*D_+tid]=a0; wimg[b*D_+tid+256]=a1;
    wimg[b*D_+tid+512]=a2; wimg[b*D_+tid+768]=a3;
  }
  gsync(bar,6);

  // ---- S6: v-chain: (wimg+cond)@Wv
  gemm_unit<D_,0,0,1,0>(wimg,cond,Wv,nullptr,v, bid&7, bid>>3, smem, nullptr,nullptr);
  gsync(bar,7);

  // ---- S7: newemb = v@Wp + bp
  gemm_unit<D_,0,0,0,0>(v,nullptr,Wp,bp,nemb, bid&7, bid>>3, smem, nullptr,nullptr);
  gsync(bar,8);

  // ---- S8: r = newemb@Wd1_top + bd1 (2 units/block) with fused p0 epilogue
  {
    int u0=bid, u1=bid+NB_;
    gemm_unit<TWOD_,0,0,0,1>(nemb,nullptr,Wd1,bd1,rb, u0&15, u0>>4, smem, Wd2, p0);
    gemm_unit<TWOD_,0,0,0,1>(nemb,nullptr,Wd1,bd1,rb, u1&15, u1>>4, smem, Wd2, p0);
  }
  gsync(bar,9);

  // ---- S9: exact sparse decoder correction
  {
    int jc = bid&7, yg = bid>>3;
    int j = jc*256 + tid;
    float wd2j = Wd2[j];
    int c = min(__hip_atomic_load(cnt,__ATOMIC_RELAXED,__HIP_MEMORY_SCOPE_AGENT), ROWS_);
    float* img = smem;          // [1024][8]: img[i*8+u]
    float* red = smem + 8192;
    for (int base = yg*8; base < c; base += 64*8){
      int nu = min(8, c-base);
      __syncthreads();
      for (int u=0;u<nu;u++){
        const float* src = imgf + (size_t)lrow[base+u]*D_;
        for (int i=tid;i<D_;i+=NT_) img[i*8+u]=src[i];
      }
      for (int u=nu;u<8;u++)
        for (int i=tid;i<D_;i+=NT_) img[i*8+u]=0.f;
      __syncthreads();
      float g[8];
      #pragma unroll
      for (int u=0;u<8;u++) g[u]=0.f;
      const float* wp = Wd1 + (size_t)D_*TWOD_ + j;
      #pragma unroll 4
      for (int e=0;e<D_;e++){
        float wv = wp[(size_t)e*TWOD_];
        const float4* ir = (const float4*)(&img[e*8]);
        float4 i0=ir[0], i1=ir[1];
        g[0]=fmaf(i0.x,wv,g[0]); g[1]=fmaf(i0.y,wv,g[1]);
        g[2]=fmaf(i0.z,wv,g[2]); g[3]=fmaf(i0.w,wv,g[3]);
        g[4]=fmaf(i1.x,wv,g[4]); g[5]=fmaf(i1.y,wv,g[5]);
        g[6]=fmaf(i1.z,wv,g[6]); g[7]=fmaf(i1.w,wv,g[7]);
      }
      for (int u=0;u<nu;u++){
        int row=lrow[base+u];
        float rv = rb[(size_t)(row/N_)*TWOD_ + j];
        float cc = rv + liw[base+u]*g[u];
        float contrib = (fmaxf(cc,0.f)-fmaxf(rv,0.f))*wd2j;
        contrib = wrsum(contrib);
        if (lane==0) red[wid]=contrib;
        __syncthreads();
        if (tid==0) atomicAdd(&pcorr[row], red[0]+red[1]+red[2]+red[3]);
        __syncthreads();
      }
    }
  }
  gsync(bar,10);

  // ---- S10: out = p0[b] + bd2 + pcorr + weight
  {
    int t = bid*NT_ + tid;
    if (t < ROWS_){
      int b = t/N_;
      out[t] = p0[b] + bd2[0] + pcorr[t] + wgt[t];
    }
  }
}

extern "C" void kernel_launch(void* const* d_in, const int* in_sizes, int n_in,
                              void* d_out, int out_size, void* d_ws, size_t ws_size,
                              hipStream_t stream) {
  const float* x    = (const float*)d_in[0];
  const int*   ts   = (const int*)  d_in[1];
  const float* text = (const float*)d_in[2];
  const float* imgf = (const float*)d_in[3];
  const float* Wq   = (const float*)d_in[4];
  const float* Wk   = (const float*)d_in[5];
  const float* Wv   = (const float*)d_in[6];
  const float* Wp   = (const float*)d_in[7];
  const float* bp   = (const float*)d_in[8];
  const float* Wt1  = (const float*)d_in[9];
  const float* bt1  = (const float*)d_in[10];
  const float* Wt2  = (const float*)d_in[11];
  const float* bt2  = (const float*)d_in[12];
  const float* Wd1  = (const float*)d_in[13];
  const float* bd1  = (const float*)d_in[14];
  const float* Wd2  = (const float*)d_in[15];
  const float* bd2  = (const float*)d_in[16];
  float* out = (float*)d_out;
  float* ws  = (float*)d_ws;

  // zero the grid-barrier counter (capture-safe async memset)
  hipMemsetAsync((char*)d_ws + (size_t)1679552*4, 0, 256, stream);

  k_mega<<<NB_,NT_,0,stream>>>(x, ts, text, imgf, Wq, Wk, Wv, Wp, bp,
                               Wt1, bt1, Wt2, bt2, Wd1, bd1, Wd2, bd2,
                               out, ws);
}

// Round 3
// 1161.033 us; speedup vs baseline: 1.4773x; 1.4773x over previous
//
#include <hip/hip_runtime.h>
#include <cmath>

#define D_    1024
#define B_    128
#define N_    576
#define ROWS_ (B_*N_)
#define TWOD_ 2048
#define TAU_  1e-5f
#define NB_   512
#define NT_   256

__device__ __forceinline__ float wrsum(float v){
  #pragma unroll
  for (int m=32;m;m>>=1) v += __shfl_xor(v,m,64);
  return v;
}
__device__ __forceinline__ float wrmax(float v){
  #pragma unroll
  for (int m=32;m;m>>=1) v = fmaxf(v,__shfl_xor(v,m,64));
  return v;
}

// device-scope grid barrier, low-overhead:
// - RELAXED fetch_add (release provided by explicit __threadfence once)
// - RELAXED polls (no per-poll cache maintenance! ACQUIRE polls invalidate L2
//   continuously and thrash co-resident workers -- the round-2 bug)
// - single final ACQUIRE load provides the acquire side.
__device__ __forceinline__ void gsync(int* bar, int phase){
  __syncthreads();
  if (threadIdx.x==0){
    __threadfence();  // release: prior stores visible device-wide
    __hip_atomic_fetch_add(bar, 1, __ATOMIC_RELAXED, __HIP_MEMORY_SCOPE_AGENT);
    while (__hip_atomic_load(bar, __ATOMIC_RELAXED, __HIP_MEMORY_SCOPE_AGENT) < NB_*phase)
      __builtin_amdgcn_s_sleep(16);
    (void)__hip_atomic_load(bar, __ATOMIC_ACQUIRE, __HIP_MEMORY_SCOPE_AGENT);
  }
  __syncthreads();
}

// one 2-row x 128-col GEMM tile: C[2,NOUT tile] = act((A(+A2))@W + bias)
// TMODE 0: W[k*NOUT+col]; TMODE 1: W[col*D_+k] (A@W^T). DOP0: fuse p0 += relu(o)*wd2.
// GENA: synthesize A rows as pe[ts[row]] (sin/cos) directly into LDS.
template<int NOUT,int ACT,int TMODE,int FUSEADD,int DOP0,int GENA>
__device__ void gemm_unit(const float* A, const float* A2, const float* W,
    const float* bias, float* C, int bx, int by, float* a_s,
    const float* wd2, float* p0, const int* ts){
  int tid = threadIdx.x;
  int r0 = by*2;
  if (GENA){
    #pragma unroll
    for (int r=0;r<2;r++){
      float tt = (float)ts[r0+r];
      for (int i=tid;i<512;i+=NT_){
        float dv = expf((float)(2*i) * (-9.210340371976184f/1024.f));
        float a = tt*dv;
        a_s[r*D_+2*i]   = sinf(a);
        a_s[r*D_+2*i+1] = cosf(a);
      }
    }
  } else if (FUSEADD){
    const float4* A4 = (const float4*)(A + (size_t)r0*D_);
    const float4* B4 = (const float4*)(A2 + (size_t)r0*D_);
    float4* s4 = (float4*)a_s;
    for (int i=tid;i<512;i+=NT_){ float4 a=A4[i], b=B4[i];
      s4[i] = make_float4(a.x+b.x,a.y+b.y,a.z+b.z,a.w+b.w); }
  } else {
    const float4* A4 = (const float4*)(A + (size_t)r0*D_);
    float4* s4 = (float4*)a_s;
    for (int i=tid;i<512;i+=NT_) s4[i]=A4[i];
  }
  __syncthreads();
  int rsel = tid>>7;
  int row = r0 + rsel;
  int col = bx*128 + (tid&127);
  const float* arow = a_s + rsel*D_;
  float acc0=0.f, acc1=0.f, acc2=0.f, acc3=0.f;   // 4 chains: ILP
  if (TMODE==0){
    const float* wp = W + col;
    #pragma unroll 8
    for (int k=0;k<D_;k+=4){
      acc0 = fmaf(arow[k],   wp[(size_t)k*NOUT],     acc0);
      acc1 = fmaf(arow[k+1], wp[(size_t)(k+1)*NOUT], acc1);
      acc2 = fmaf(arow[k+2], wp[(size_t)(k+2)*NOUT], acc2);
      acc3 = fmaf(arow[k+3], wp[(size_t)(k+3)*NOUT], acc3);
    }
  } else {
    const float* wp = W + (size_t)col*D_;
    #pragma unroll 8
    for (int k=0;k<D_;k+=4){
      float4 wv = *(const float4*)(wp+k);
      acc0=fmaf(arow[k],  wv.x,acc0); acc1=fmaf(arow[k+1],wv.y,acc1);
      acc2=fmaf(arow[k+2],wv.z,acc2); acc3=fmaf(arow[k+3],wv.w,acc3);
    }
  }
  float o = (acc0+acc1)+(acc2+acc3) + (bias ? bias[col] : 0.f);
  if (ACT==1) o = o/(1.f+expf(-o));
  C[(size_t)row*NOUT + col] = o;
  if (DOP0){
    float c = fmaxf(o,0.f)*wd2[col];
    c = wrsum(c);
    if ((tid&63)==0) atomicAdd(&p0[row], c);
  }
  __syncthreads();  // protect smem before reuse
}

__global__ __launch_bounds__(NT_,2) void k_mega(
  const float* __restrict__ x, const int* __restrict__ ts,
  const float* __restrict__ text, const float* __restrict__ imgf,
  const float* __restrict__ Wq, const float* __restrict__ Wk,
  const float* __restrict__ Wv, const float* __restrict__ Wp, const float* __restrict__ bp,
  const float* __restrict__ Wt1, const float* __restrict__ bt1,
  const float* __restrict__ Wt2, const float* __restrict__ bt2,
  const float* __restrict__ Wd1, const float* __restrict__ bd1,
  const float* __restrict__ Wd2, const float* __restrict__ bd2,
  float* __restrict__ out, float* __restrict__ ws)
{
  __shared__ __align__(16) float smem[8256];   // 33 KB: corr img[1024][8] is the max user
  float* h1    = ws + 131072;
  float* cond  = ws + 262144;
  float* q     = ws + 393216;
  float* kq    = ws + 524288;
  float* wimg  = ws + 655360;
  float* v     = ws + 786432;
  float* nemb  = ws + 917504;
  float* rb    = ws + 1048576;   // [B][2048]
  float* sbuf  = ws + 1310720;
  float* wgt   = ws + 1384448;
  float* pcorr = ws + 1458176;
  float* liw   = ws + 1531904;
  int*   lrow  = (int*)(ws + 1605632);
  float* p0    = ws + 1679360;
  int*   cnt   = (int*)(ws + 1679488);
  int*   bar   = (int*)(ws + 1679552);

  const int bid = blockIdx.x, tid = threadIdx.x;
  const int lane = tid&63, wid = tid>>6;

  // ---- S1: gemm Wt1 (temb synthesized in staging) + i_w logits dots + zero scratch
  gemm_unit<D_,1,0,0,0,1>(nullptr,nullptr,Wt1,bt1,h1, bid&7, bid>>3, smem, nullptr,nullptr, ts);
  {
    int wg = bid*4 + wid;
    for (int row = wg; row < ROWS_; row += NB_*4){
      const float4* ip = (const float4*)(imgf + (size_t)row*D_);
      const float4* tp = (const float4*)(text + (size_t)(row/N_)*D_);
      float acc=0.f;
      #pragma unroll
      for (int p=0;p<4;p++){
        float4 a=ip[p*64+lane], t=tp[p*64+lane];
        acc=fmaf(a.x,t.x,acc); acc=fmaf(a.y,t.y,acc);
        acc=fmaf(a.z,t.z,acc); acc=fmaf(a.w,t.w,acc);
      }
      acc = wrsum(acc);
      if (lane==0) sbuf[row]=acc;
    }
    int t = bid*NT_ + tid;
    if (t < ROWS_) pcorr[t]=0.f;
    if (t < B_)    p0[t]=0.f;
    if (t==0)      *cnt = 0;
  }
  gsync(bar,1);

  // ---- S2: gemm Wt2 -> cond; blocks<128 also do i_w softmax + build sparse list
  gemm_unit<D_,0,0,0,0,0>(h1,nullptr,Wt2,bt2,cond, bid&7, bid>>3, smem, nullptr,nullptr, nullptr);
  if (bid < B_){
    const float* sp = sbuf + bid*N_;
    float* red = smem;
    float m=-3e38f;
    for (int i=tid;i<N_;i+=NT_) m=fmaxf(m,sp[i]);
    m = wrmax(m);
    if (lane==0) red[wid]=m;
    __syncthreads();
    m = fmaxf(fmaxf(red[0],red[1]),fmaxf(red[2],red[3]));
    __syncthreads();
    float s=0.f;
    for (int i=tid;i<N_;i+=NT_) s += expf(sp[i]-m);
    s = wrsum(s);
    if (lane==0) red[wid]=s;
    __syncthreads();
    s = red[0]+red[1]+red[2]+red[3];
    float inv = 1.f/s;
    for (int i=tid;i<N_;i+=NT_){
      float wi = expf(sp[i]-m)*inv;
      if (wi > TAU_){
        int pos = atomicAdd(cnt,1);
        if (pos < ROWS_){ lrow[pos]=bid*N_+i; liw[pos]=wi; }
      }
    }
  }
  gsync(bar,2);

  // ---- S3: q = (text+cond)@Wq
  gemm_unit<D_,0,0,1,0,0>(text,cond,Wq,nullptr,q, bid&7, bid>>3, smem, nullptr,nullptr, nullptr);
  gsync(bar,3);

  // ---- S4: kq = q@Wk^T
  gemm_unit<D_,0,1,0,0,0>(q,nullptr,Wk,nullptr,kq, bid&7, bid>>3, smem, nullptr,nullptr, nullptr);
  gsync(bar,4);

  // ---- S5: per-b fused attention logits + softmax2 + wimg (no atomics, no zero-init)
  if (bid < B_){
    int b = bid;
    float* kqs  = smem;                 // 1024
    float* srow = smem+1024;            // 576
    float* red  = smem+1600;            // 8
    int*   mcv  = (int*)(smem+1608);
    int*   mrow = (int*)(smem+1664);    // up to 576
    float* miw  = smem+2240;            // up to 576
    for (int i=tid;i<D_;i+=NT_) kqs[i]=kq[b*D_+i];
    for (int j=tid;j<N_;j+=NT_) srow[j]=x[b*N_+j];
    if (tid==0) *mcv=0;
    __syncthreads();
    int c = min(__hip_atomic_load(cnt,__ATOMIC_RELAXED,__HIP_MEMORY_SCOPE_AGENT), ROWS_);
    for (int e=tid;e<c;e+=NT_){
      int row=lrow[e];
      if (row/N_ == b){
        int p = atomicAdd(mcv,1);
        mrow[p]=row; miw[p]=liw[e];
      }
    }
    __syncthreads();
    int mc = *mcv;
    for (int m=0;m<mc;m++){
      int row=mrow[m];
      const float4* ip=(const float4*)(imgf+(size_t)row*D_);
      const float4* kp=(const float4*)kqs;
      float4 a=ip[tid], k=kp[tid];
      float acc=a.x*k.x+a.y*k.y+a.z*k.z+a.w*k.w;
      acc = wrsum(acc);
      if (lane==0) red[wid]=acc;
      __syncthreads();
      if (tid==0) srow[row%N_] += miw[m]*(red[0]+red[1]+red[2]+red[3]);
      __syncthreads();
    }
    float mx=-3e38f;
    for (int j=tid;j<N_;j+=NT_) mx=fmaxf(mx,srow[j]);
    mx=wrmax(mx);
    if (lane==0) red[wid]=mx;
    __syncthreads();
    mx=fmaxf(fmaxf(red[0],red[1]),fmaxf(red[2],red[3]));
    __syncthreads();
    float sum=0.f;
    for (int j=tid;j<N_;j+=NT_) sum+=expf(srow[j]-mx);
    sum=wrsum(sum);
    if (lane==0) red[wid]=sum;
    __syncthreads();
    sum=red[0]+red[1]+red[2]+red[3];
    float inv=1.f/sum;
    __syncthreads();
    for (int j=tid;j<N_;j+=NT_){
      float wv=expf(srow[j]-mx)*inv;
      wgt[b*N_+j]=wv;
      srow[j]=wv;
    }
    __syncthreads();
    float a0=0,a1=0,a2=0,a3=0;
    for (int m=0;m<mc;m++){
      int row=mrow[m];
      float coef = miw[m]*srow[row%N_];
      const float* ip = imgf + (size_t)row*D_;
      a0=fmaf(coef,ip[tid],a0);
      a1=fmaf(coef,ip[tid+256],a1);
      a2=fmaf(coef,ip[tid+512],a2);
      a3=fmaf(coef,ip[tid+768],a3);
    }
    wimg[b*D_+tid]=a0; wimg[b*D_+tid+256]=a1;
    wimg[b*D_+tid+512]=a2; wimg[b*D_+tid+768]=a3;
  }
  gsync(bar,5);

  // ---- S6: v-chain: (wimg+cond)@Wv
  gemm_unit<D_,0,0,1,0,0>(wimg,cond,Wv,nullptr,v, bid&7, bid>>3, smem, nullptr,nullptr, nullptr);
  gsync(bar,6);

  // ---- S7: newemb = v@Wp + bp
  gemm_unit<D_,0,0,0,0,0>(v,nullptr,Wp,bp,nemb, bid&7, bid>>3, smem, nullptr,nullptr, nullptr);
  gsync(bar,7);

  // ---- S8: r = newemb@Wd1_top + bd1 (2 units/block) with fused p0 epilogue
  {
    int u0=bid, u1=bid+NB_;
    gemm_unit<TWOD_,0,0,0,1,0>(nemb,nullptr,Wd1,bd1,rb, u0&15, u0>>4, smem, Wd2, p0, nullptr);
    gemm_unit<TWOD_,0,0,0,1,0>(nemb,nullptr,Wd1,bd1,rb, u1&15, u1>>4, smem, Wd2, p0, nullptr);
  }
  gsync(bar,8);

  // ---- S9: exact sparse decoder correction
  {
    int jc = bid&7, yg = bid>>3;
    int j = jc*256 + tid;
    float wd2j = Wd2[j];
    int c = min(__hip_atomic_load(cnt,__ATOMIC_RELAXED,__HIP_MEMORY_SCOPE_AGENT), ROWS_);
    float* img = smem;          // [1024][8]: img[i*8+u]
    float* red = smem + 8192;
    for (int base = yg*8; base < c; base += 64*8){
      int nu = min(8, c-base);
      __syncthreads();
      for (int u=0;u<nu;u++){
        const float* src = imgf + (size_t)lrow[base+u]*D_;
        for (int i=tid;i<D_;i+=NT_) img[i*8+u]=src[i];
      }
      for (int u=nu;u<8;u++)
        for (int i=tid;i<D_;i+=NT_) img[i*8+u]=0.f;
      __syncthreads();
      float g[8];
      #pragma unroll
      for (int u=0;u<8;u++) g[u]=0.f;
      const float* wp = Wd1 + (size_t)D_*TWOD_ + j;
      #pragma unroll 8
      for (int e=0;e<D_;e++){
        float wv = wp[(size_t)e*TWOD_];
        const float4* ir = (const float4*)(&img[e*8]);
        float4 i0=ir[0], i1=ir[1];
        g[0]=fmaf(i0.x,wv,g[0]); g[1]=fmaf(i0.y,wv,g[1]);
        g[2]=fmaf(i0.z,wv,g[2]); g[3]=fmaf(i0.w,wv,g[3]);
        g[4]=fmaf(i1.x,wv,g[4]); g[5]=fmaf(i1.y,wv,g[5]);
        g[6]=fmaf(i1.z,wv,g[6]); g[7]=fmaf(i1.w,wv,g[7]);
      }
      for (int u=0;u<nu;u++){
        int row=lrow[base+u];
        float rv = rb[(size_t)(row/N_)*TWOD_ + j];
        float cc = rv + liw[base+u]*g[u];
        float contrib = (fmaxf(cc,0.f)-fmaxf(rv,0.f))*wd2j;
        contrib = wrsum(contrib);
        if (lane==0) red[wid]=contrib;
        __syncthreads();
        if (tid==0) atomicAdd(&pcorr[row], red[0]+red[1]+red[2]+red[3]);
        __syncthreads();
      }
    }
  }
  gsync(bar,9);

  // ---- S10: out = p0[b] + bd2 + pcorr + weight
  {
    int t = bid*NT_ + tid;
    if (t < ROWS_){
      int b = t/N_;
      out[t] = p0[b] + bd2[0] + pcorr[t] + wgt[t];
    }
  }
}

extern "C" void kernel_launch(void* const* d_in, const int* in_sizes, int n_in,
                              void* d_out, int out_size, void* d_ws, size_t ws_size,
                              hipStream_t stream) {
  const float* x    = (const float*)d_in[0];
  const int*   ts   = (const int*)  d_in[1];
  const float* text = (const float*)d_in[2];
  const float* imgf = (const float*)d_in[3];
  const float* Wq   = (const float*)d_in[4];
  const float* Wk   = (const float*)d_in[5];
  const float* Wv   = (const float*)d_in[6];
  const float* Wp   = (const float*)d_in[7];
  const float* bp   = (const float*)d_in[8];
  const float* Wt1  = (const float*)d_in[9];
  const float* bt1  = (const float*)d_in[10];
  const float* Wt2  = (const float*)d_in[11];
  const float* bt2  = (const float*)d_in[12];
  const float* Wd1  = (const float*)d_in[13];
  const float* bd1  = (const float*)d_in[14];
  const float* Wd2  = (const float*)d_in[15];
  const float* bd2  = (const float*)d_in[16];
  float* out = (float*)d_out;
  float* ws  = (float*)d_ws;

  // zero the grid-barrier counter (capture-safe async memset)
  hipMemsetAsync((char*)d_ws + (size_t)1679552*4, 0, 256, stream);

  k_mega<<<NB_,NT_,0,stream>>>(x, ts, text, imgf, Wq, Wk, Wv, Wp, bp,
                               Wt1, bt1, Wt2, bt2, Wd1, bd1, Wd2, bd2,
                               out, ws);
}

// Round 4
// 978.524 us; speedup vs baseline: 1.7528x; 1.1865x over previous
//
#include <hip/hip_runtime.h>
#include <cmath>

#define D_    1024
#define B_    128
#define N_    576
#define ROWS_ (B_*N_)
#define TWOD_ 2048
#define TAU_  1e-5f
#define NB_   512
#define NT_   256

__device__ __forceinline__ float wrsum(float v){
  #pragma unroll
  for (int m=32;m;m>>=1) v += __shfl_xor(v,m,64);
  return v;
}
__device__ __forceinline__ float wrmax(float v){
  #pragma unroll
  for (int m=32;m;m>>=1) v = fmaxf(v,__shfl_xor(v,m,64));
  return v;
}

// device-scope grid barrier: relaxed arrive + relaxed polls (no per-poll cache
// maintenance), single trailing acquire load. Proven correct in round 3.
__device__ __forceinline__ void gsync(int* bar, int phase){
  __syncthreads();
  if (threadIdx.x==0){
    __threadfence();
    __hip_atomic_fetch_add(bar, 1, __ATOMIC_RELAXED, __HIP_MEMORY_SCOPE_AGENT);
    while (__hip_atomic_load(bar, __ATOMIC_RELAXED, __HIP_MEMORY_SCOPE_AGENT) < NB_*phase)
      __builtin_amdgcn_s_sleep(16);
    (void)__hip_atomic_load(bar, __ATOMIC_ACQUIRE, __HIP_MEMORY_SCOPE_AGENT);
  }
  __syncthreads();
}

// ---------------- K-split GEMM unit ----------------
// Tile: 8 rows x 128 cols x K-chunk 256. W row-major [K][NOUT], float4 along N.
// Partials atomicAdd'ed into pre-zeroed C; bias added by kz==0 unit.
// SRC: 0 = A; 1 = A+A2 (fused add); 2 = synthesize temb=pe[ts] in staging.
// SACT: 1 = apply silu to staged A values (activation deferred from producer).
// Needs a_s >= 4096 floats.
template<int NOUT,int SRC,int SACT>
__device__ void gemm_ks(const float* A, const float* A2, const float* W,
    const float* bias, float* C, int bx, int byr, int kz, float* a_s,
    const int* ts){
  const int tid=threadIdx.x, lane=tid&63, w=tid>>6;
  const int r0=byr*8, k0=kz*256;
  // ---- stage A[8][256] into LDS
  if (SRC==2){
    for (int i=tid;i<2048;i+=NT_){
      int r=i>>8, kk=i&255, d=k0+kk;
      float tt=(float)ts[r0+r];
      float dv=expf((float)(d&~1)*(-9.210340371976184f/1024.f));
      float a=tt*dv;
      a_s[i]=(d&1)?cosf(a):sinf(a);
    }
  } else if (SRC==1){
    const float4* A4=(const float4*)A; const float4* B4=(const float4*)A2;
    for (int i=tid;i<512;i+=NT_){
      int r=i>>6, kk4=i&63;
      float4 a=A4[(size_t)(r0+r)*256 + (k0>>2)+kk4];
      float4 b=B4[(size_t)(r0+r)*256 + (k0>>2)+kk4];
      ((float4*)a_s)[i]=make_float4(a.x+b.x,a.y+b.y,a.z+b.z,a.w+b.w);
    }
  } else {
    const float4* A4=(const float4*)A;
    for (int i=tid;i<512;i+=NT_){
      int r=i>>6, kk4=i&63;
      float4 a=A4[(size_t)(r0+r)*256 + (k0>>2)+kk4];
      if (SACT){
        a.x=a.x/(1.f+expf(-a.x)); a.y=a.y/(1.f+expf(-a.y));
        a.z=a.z/(1.f+expf(-a.z)); a.w=a.w/(1.f+expf(-a.w));
      }
      ((float4*)a_s)[i]=a;
    }
  }
  __syncthreads();
  // ---- compute: wave w owns k-sub [w*64, w*64+64); lane: kh=lane>>5 (k parity),
  // c4=lane&31 (4-col group). Wave load = 2 x 512B contiguous segments.
  const int c4=lane&31, kh=lane>>5;
  const float* wbase = W + (size_t)(k0 + w*64 + kh)*NOUT + bx*128 + c4*4;
  float acc[8][4];
  #pragma unroll
  for (int r=0;r<8;r++){ acc[r][0]=0.f;acc[r][1]=0.f;acc[r][2]=0.f;acc[r][3]=0.f; }
  const float* arow = a_s + w*64 + kh;
  #pragma unroll 4
  for (int it=0; it<32; it++){
    float4 wv = *(const float4*)(wbase + (size_t)(it*2)*NOUT);
    #pragma unroll
    for (int r=0;r<8;r++){
      float av = arow[r*256 + it*2];
      acc[r][0]=fmaf(av,wv.x,acc[r][0]);
      acc[r][1]=fmaf(av,wv.y,acc[r][1]);
      acc[r][2]=fmaf(av,wv.z,acc[r][2]);
      acc[r][3]=fmaf(av,wv.w,acc[r][3]);
    }
  }
  // fold k-parity lane pairs (L, L^32)
  #pragma unroll
  for (int r=0;r<8;r++){
    #pragma unroll
    for (int cc=0;cc<4;cc++) acc[r][cc] += __shfl_xor(acc[r][cc],32,64);
  }
  __syncthreads();                       // a_s reuse as partial buffer
  float* part = a_s;                     // [4][8][128] = 4096 floats
  if (lane<32){
    #pragma unroll
    for (int r=0;r<8;r++)
      ((float4*)part)[(w*1024 + r*128 + c4*4)>>2] =
        make_float4(acc[r][0],acc[r][1],acc[r][2],acc[r][3]);
  }
  __syncthreads();
  const float* bp2 = (kz==0)? bias : nullptr;
  for (int o=tid;o<1024;o+=NT_){
    int r=o>>7, c=o&127;
    float v0 = part[r*128+c] + part[1024+r*128+c] + part[2048+r*128+c] + part[3072+r*128+c];
    if (bp2) v0 += bp2[bx*128+c];
    atomicAdd(&C[(size_t)(r0+r)*NOUT + bx*128 + c], v0);
  }
  __syncthreads();
}

// ---------------- full-K transposed-access unit (kq = q @ Wk^T) ----------------
// 2 rows x 128 cols, W[col*D_+k] contiguous per thread. Direct write.
__device__ void gemm_t(const float* A, const float* W, float* C,
    int bx, int by, float* a_s){
  int tid=threadIdx.x;
  int r0=by*2;
  const float4* A4=(const float4*)(A + (size_t)r0*D_);
  float4* s4=(float4*)a_s;
  for (int i=tid;i<512;i+=NT_) s4[i]=A4[i];
  __syncthreads();
  int rsel=tid>>7;
  int row=r0+rsel;
  int col=bx*128+(tid&127);
  const float* arow=a_s+rsel*D_;
  const float* wp=W+(size_t)col*D_;
  float a0=0.f,a1=0.f,a2=0.f,a3=0.f;
  #pragma unroll 8
  for (int k=0;k<D_;k+=4){
    float4 wv=*(const float4*)(wp+k);
    a0=fmaf(arow[k],wv.x,a0); a1=fmaf(arow[k+1],wv.y,a1);
    a2=fmaf(arow[k+2],wv.z,a2); a3=fmaf(arow[k+3],wv.w,a3);
  }
  C[(size_t)row*D_+col]=(a0+a1)+(a2+a3);
  __syncthreads();
}

__global__ __launch_bounds__(NT_,2) void k_mega(
  const float* __restrict__ x, const int* __restrict__ ts,
  const float* __restrict__ text, const float* __restrict__ imgf,
  const float* __restrict__ Wq, const float* __restrict__ Wk,
  const float* __restrict__ Wv, const float* __restrict__ Wp, const float* __restrict__ bp,
  const float* __restrict__ Wt1, const float* __restrict__ bt1,
  const float* __restrict__ Wt2, const float* __restrict__ bt2,
  const float* __restrict__ Wd1, const float* __restrict__ bd1,
  const float* __restrict__ Wd2, const float* __restrict__ bd2,
  float* __restrict__ out, float* __restrict__ ws)
{
  __shared__ __align__(16) float smem[8256];
  float* sbuf  = ws;                        // [73728]
  float* wgt   = ws + 73728;                // [73728]
  float* liw   = ws + 147456;               // [73728]
  int*   lrow  = (int*)(ws + 221184);       // [73728]
  float* kq    = ws + 294912;               // [131072]
  float* wimg  = ws + 425984;               // [131072]
  // ---- zero-region (memset by host) starts here ----
  float* h1    = ws + 557056;               // [131072]
  float* cond  = ws + 688128;               // [131072]
  float* q     = ws + 819200;               // [131072]
  float* v     = ws + 950272;               // [131072]
  float* nemb  = ws + 1081344;              // [131072]
  float* rb    = ws + 1212416;              // [262144]  [B][2048]
  float* pcorr = ws + 1474560;              // [73728]
  float* p0    = ws + 1548288;              // [128]
  int*   cnt   = (int*)(ws + 1548416);      // [64]
  int*   bar   = (int*)(ws + 1548480);      // [64]

  const int bid=blockIdx.x, tid=threadIdx.x;
  const int lane=tid&63, wid=tid>>6;
  // unit decode for NOUT=1024: bx=u&7, byr=(u>>3)&15, kz=u>>7
  const int bx8=bid&7, byr8=(bid>>3)&15, kz8=bid>>7;

  // ---- S1: h1 = silu-deferred(temb@Wt1+bt1) [k-split] + i_w logit dots
  gemm_ks<D_,2,0>(nullptr,nullptr,Wt1,bt1,h1, bx8,byr8,kz8, smem, ts);
  {
    int wg = bid*4 + wid;
    for (int row=wg; row<ROWS_; row+=NB_*4){
      const float4* ip=(const float4*)(imgf+(size_t)row*D_);
      const float4* tp=(const float4*)(text+(size_t)(row/N_)*D_);
      float acc=0.f;
      #pragma unroll
      for (int p=0;p<4;p++){
        float4 a=ip[p*64+lane], t=tp[p*64+lane];
        acc=fmaf(a.x,t.x,acc); acc=fmaf(a.y,t.y,acc);
        acc=fmaf(a.z,t.z,acc); acc=fmaf(a.w,t.w,acc);
      }
      acc=wrsum(acc);
      if (lane==0) sbuf[row]=acc;
    }
  }
  gsync(bar,1);

  // ---- S2: cond = silu(h1)@Wt2+bt2 [k-split, silu in staging]; blocks<128: i_w softmax + list
  gemm_ks<D_,0,1>(h1,nullptr,Wt2,bt2,cond, bx8,byr8,kz8, smem, nullptr);
  if (bid < B_){
    const float* sp = sbuf + bid*N_;
    float* red = smem;
    float m=-3e38f;
    for (int i=tid;i<N_;i+=NT_) m=fmaxf(m,sp[i]);
    m=wrmax(m);
    if (lane==0) red[wid]=m;
    __syncthreads();
    m=fmaxf(fmaxf(red[0],red[1]),fmaxf(red[2],red[3]));
    __syncthreads();
    float s=0.f;
    for (int i=tid;i<N_;i+=NT_) s+=expf(sp[i]-m);
    s=wrsum(s);
    if (lane==0) red[wid]=s;
    __syncthreads();
    s=red[0]+red[1]+red[2]+red[3];
    float inv=1.f/s;
    for (int i=tid;i<N_;i+=NT_){
      float wi=expf(sp[i]-m)*inv;
      if (wi>TAU_){
        int pos=atomicAdd(cnt,1);
        if (pos<ROWS_){ lrow[pos]=bid*N_+i; liw[pos]=wi; }
      }
    }
  }
  gsync(bar,2);

  // ---- S3: q = (text+cond)@Wq [k-split, fused add]
  gemm_ks<D_,1,0>(text,cond,Wq,nullptr,q, bx8,byr8,kz8, smem, nullptr);
  gsync(bar,3);

  // ---- S4: kq = q@Wk^T (full-K, contiguous per-thread)
  gemm_t(q,Wk,kq, bid&7, bid>>3, smem);
  gsync(bar,4);

  // ---- S5: per-b attention logits + softmax + wimg (blocks<128)
  if (bid < B_){
    int b=bid;
    float* kqs  = smem;
    float* srow = smem+1024;
    float* red  = smem+1600;
    int*   mcv  = (int*)(smem+1608);
    int*   mrow = (int*)(smem+1664);
    float* miw  = smem+2240;
    for (int i=tid;i<D_;i+=NT_) kqs[i]=kq[b*D_+i];
    for (int j=tid;j<N_;j+=NT_) srow[j]=x[b*N_+j];
    if (tid==0) *mcv=0;
    __syncthreads();
    int c = min(__hip_atomic_load(cnt,__ATOMIC_RELAXED,__HIP_MEMORY_SCOPE_AGENT), ROWS_);
    for (int e=tid;e<c;e+=NT_){
      int row=lrow[e];
      if (row/N_==b){
        int p=atomicAdd(mcv,1);
        mrow[p]=row; miw[p]=liw[e];
      }
    }
    __syncthreads();
    int mc=*mcv;
    for (int m=0;m<mc;m++){
      int row=mrow[m];
      const float4* ip=(const float4*)(imgf+(size_t)row*D_);
      const float4* kp=(const float4*)kqs;
      float4 a=ip[tid], k=kp[tid];
      float acc=a.x*k.x+a.y*k.y+a.z*k.z+a.w*k.w;
      acc=wrsum(acc);
      if (lane==0) red[wid]=acc;
      __syncthreads();
      if (tid==0) srow[row%N_] += miw[m]*(red[0]+red[1]+red[2]+red[3]);
      __syncthreads();
    }
    float mx=-3e38f;
    for (int j=tid;j<N_;j+=NT_) mx=fmaxf(mx,srow[j]);
    mx=wrmax(mx);
    if (lane==0) red[wid]=mx;
    __syncthreads();
    mx=fmaxf(fmaxf(red[0],red[1]),fmaxf(red[2],red[3]));
    __syncthreads();
    float sum=0.f;
    for (int j=tid;j<N_;j+=NT_) sum+=expf(srow[j]-mx);
    sum=wrsum(sum);
    if (lane==0) red[wid]=sum;
    __syncthreads();
    sum=red[0]+red[1]+red[2]+red[3];
    float inv=1.f/sum;
    __syncthreads();
    for (int j=tid;j<N_;j+=NT_){
      float wv=expf(srow[j]-mx)*inv;
      wgt[b*N_+j]=wv;
      srow[j]=wv;
    }
    __syncthreads();
    float a0=0,a1=0,a2=0,a3=0;
    for (int m=0;m<mc;m++){
      int row=mrow[m];
      float coef=miw[m]*srow[row%N_];
      const float* ip=imgf+(size_t)row*D_;
      a0=fmaf(coef,ip[tid],a0);
      a1=fmaf(coef,ip[tid+256],a1);
      a2=fmaf(coef,ip[tid+512],a2);
      a3=fmaf(coef,ip[tid+768],a3);
    }
    wimg[b*D_+tid]=a0; wimg[b*D_+tid+256]=a1;
    wimg[b*D_+tid+512]=a2; wimg[b*D_+tid+768]=a3;
  }
  gsync(bar,5);

  // ---- S6: v = (wimg+cond)@Wv [k-split]
  gemm_ks<D_,1,0>(wimg,cond,Wv,nullptr,v, bx8,byr8,kz8, smem, nullptr);
  gsync(bar,6);

  // ---- S7: nemb = v@Wp + bp [k-split]
  gemm_ks<D_,0,0>(v,nullptr,Wp,bp,nemb, bx8,byr8,kz8, smem, nullptr);
  gsync(bar,7);

  // ---- S8: rb = nemb@Wd1_top + bd1 [k-split, NOUT=2048, 2 units/block]
  {
    int u0=bid, u1=bid+NB_;
    gemm_ks<TWOD_,0,0>(nemb,nullptr,Wd1,bd1,rb, u0&15,(u0>>4)&15,u0>>8, smem, nullptr);
    gemm_ks<TWOD_,0,0>(nemb,nullptr,Wd1,bd1,rb, u1&15,(u1>>4)&15,u1>>8, smem, nullptr);
  }
  gsync(bar,8);

  // ---- S9: blocks 0..383: exact sparse decoder correction; blocks 384..511: p0
  if (bid < 384){
    int jc=bid&7, yg=bid>>3;          // yg in [0,48)
    int j=jc*256+tid;
    float wd2j=Wd2[j];
    int c = min(__hip_atomic_load(cnt,__ATOMIC_RELAXED,__HIP_MEMORY_SCOPE_AGENT), ROWS_);
    float* img=smem;                  // [1024][8]
    float* red=smem+8192;
    for (int base=yg*8; base<c; base+=48*8){
      int nu=min(8,c-base);
      __syncthreads();
      for (int u=0;u<nu;u++){
        const float* src=imgf+(size_t)lrow[base+u]*D_;
        for (int i=tid;i<D_;i+=NT_) img[i*8+u]=src[i];
      }
      for (int u=nu;u<8;u++)
        for (int i=tid;i<D_;i+=NT_) img[i*8+u]=0.f;
      __syncthreads();
      float g[8];
      #pragma unroll
      for (int u=0;u<8;u++) g[u]=0.f;
      const float* wp=Wd1+(size_t)D_*TWOD_+j;
      #pragma unroll 8
      for (int e=0;e<D_;e++){
        float wv=wp[(size_t)e*TWOD_];
        const float4* ir=(const float4*)(&img[e*8]);
        float4 i0=ir[0], i1=ir[1];
        g[0]=fmaf(i0.x,wv,g[0]); g[1]=fmaf(i0.y,wv,g[1]);
        g[2]=fmaf(i0.z,wv,g[2]); g[3]=fmaf(i0.w,wv,g[3]);
        g[4]=fmaf(i1.x,wv,g[4]); g[5]=fmaf(i1.y,wv,g[5]);
        g[6]=fmaf(i1.z,wv,g[6]); g[7]=fmaf(i1.w,wv,g[7]);
      }
      for (int u=0;u<nu;u++){
        int row=lrow[base+u];
        float rv=rb[(size_t)(row/N_)*TWOD_+j];
        float cc=rv+liw[base+u]*g[u];
        float contrib=(fmaxf(cc,0.f)-fmaxf(rv,0.f))*wd2j;
        contrib=wrsum(contrib);
        if (lane==0) red[wid]=contrib;
        __syncthreads();
        if (tid==0) atomicAdd(&pcorr[row], red[0]+red[1]+red[2]+red[3]);
        __syncthreads();
      }
    }
  } else {
    int b=bid-384;
    float* red=smem;
    float acc=0.f;
    for (int j=tid;j<TWOD_;j+=NT_)
      acc=fmaf(fmaxf(rb[(size_t)b*TWOD_+j],0.f), Wd2[j], acc);
    acc=wrsum(acc);
    if (lane==0) red[wid]=acc;
    __syncthreads();
    if (tid==0) p0[b]=red[0]+red[1]+red[2]+red[3];
  }
  gsync(bar,9);

  // ---- S10: out = p0[b] + bd2 + pcorr + weight
  {
    int t=bid*NT_+tid;
    if (t<ROWS_){
      int b=t/N_;
      out[t]=p0[b]+bd2[0]+pcorr[t]+wgt[t];
    }
  }
}

extern "C" void kernel_launch(void* const* d_in, const int* in_sizes, int n_in,
                              void* d_out, int out_size, void* d_ws, size_t ws_size,
                              hipStream_t stream) {
  const float* x    = (const float*)d_in[0];
  const int*   ts   = (const int*)  d_in[1];
  const float* text = (const float*)d_in[2];
  const float* imgf = (const float*)d_in[3];
  const float* Wq   = (const float*)d_in[4];
  const float* Wk   = (const float*)d_in[5];
  const float* Wv   = (const float*)d_in[6];
  const float* Wp   = (const float*)d_in[7];
  const float* bp   = (const float*)d_in[8];
  const float* Wt1  = (const float*)d_in[9];
  const float* bt1  = (const float*)d_in[10];
  const float* Wt2  = (const float*)d_in[11];
  const float* bt2  = (const float*)d_in[12];
  const float* Wd1  = (const float*)d_in[13];
  const float* bd1  = (const float*)d_in[14];
  const float* Wd2  = (const float*)d_in[15];
  const float* bd2  = (const float*)d_in[16];
  float* out = (float*)d_out;
  float* ws  = (float*)d_ws;

  // zero region: [h1 .. bar] = floats [557056, 1548544) -> one capture-safe memset
  hipMemsetAsync((char*)d_ws + (size_t)557056*4, 0, (size_t)(1548544-557056)*4, stream);

  k_mega<<<NB_,NT_,0,stream>>>(x, ts, text, imgf, Wq, Wk, Wv, Wp, bp,
                               Wt1, bt1, Wt2, bt2, Wd1, bd1, Wd2, bd2,
                               out, ws);
}